// Round 1
// baseline (201.344 us; speedup 1.0000x reference)
//
#include <hip/hip_runtime.h>
#include <stdint.h>

// Problem constants
#define D_MODEL 1024
#define NHEADS  16
#define HDIM    64
#define WINDOW  256
#define BATCH   4
#define SEQ     2048
#define NROWS   (BATCH*SEQ)   // 8192

using short8 = __attribute__((ext_vector_type(8))) short;
using f32x4  = __attribute__((ext_vector_type(4))) float;
using u32x4  = __attribute__((ext_vector_type(4))) uint32_t;
using u16x4  = __attribute__((ext_vector_type(4))) unsigned short;
typedef unsigned short u16;

__device__ __forceinline__ u16 f2b(float f) {
  union { float f; uint32_t u; } v; v.f = f;
  uint32_t r = v.u + 0x7fffu + ((v.u >> 16) & 1u);
  return (u16)(r >> 16);
}

__device__ __forceinline__ void gload_lds16(const void* g, void* l) {
  __builtin_amdgcn_global_load_lds(
      (const __attribute__((address_space(1))) uint32_t*)g,
      (__attribute__((address_space(3))) uint32_t*)l, 16, 0, 0);
}

// ---------------- conversion kernels ----------------

// fp32 -> bf16 straight cast, 4 elems/thread
__global__ void cvt_cast_kernel(const float* __restrict__ in, u16* __restrict__ out, int n4) {
  int i = blockIdx.x * blockDim.x + threadIdx.x;
  if (i < n4) {
    f32x4 v = *(const f32x4*)(in + 4 * (size_t)i);
    u16x4 o;
    o.x = f2b(v.x); o.y = f2b(v.y); o.z = f2b(v.z); o.w = f2b(v.w);
    *(u16x4*)(out + 4 * (size_t)i) = o;
  }
}

// fp32 [R][C] -> bf16 transposed [C][R]; out[n*R + k] = in[k*C + n]
__global__ void cvt_T_kernel(const float* __restrict__ in, u16* __restrict__ out, int R, int C) {
  int i = blockIdx.x * blockDim.x + threadIdx.x;
  int total = R * C;
  if (i < total) {
    int n = i / R, k = i - n * R;
    out[i] = f2b(in[(size_t)k * C + n]);
  }
}

// ---------------- GEMM (m97 structure: 128x128 tile, BK=32, 4 waves) ----------------
// A: [M][K] bf16 row-major.  BT: [N][K] bf16 row-major (pre-transposed B).
// MODE 0: QKV epilogue -> qkb [8192][2048] (cols<2048) bf16, vT [B*H][64][2048] bf16 (cols>=2048)
// MODE 1: fp32 out [M][N]
template <int MODE>
__global__ __launch_bounds__(256) void gemm_kernel(
    const u16* __restrict__ A, const u16* __restrict__ BT,
    u16* __restrict__ qkb, u16* __restrict__ vT, float* __restrict__ outf,
    int M, int N, int K) {
  __shared__ short As[128 * 32];
  __shared__ short Bs[128 * 32];
  const int tid = threadIdx.x;
  const int l = tid & 63;
  const int w = tid >> 6;
  const int wr = w >> 1, wc = w & 1;
  const int m0 = blockIdx.y * 128, n0 = blockIdx.x * 128;
  const int lr = l & 15, lk = (l >> 4) * 8;

  f32x4 acc[4][4] = {};
  const int nkt = K >> 5;
  const int c0 = w * 64 + l;
  const int c1 = 256 + c0;

  for (int kt = 0; kt < nkt; ++kt) {
    __syncthreads();
    const int kofs = kt * 32;
    gload_lds16(A + (size_t)(m0 + (c0 >> 2)) * K + kofs + (c0 & 3) * 8, &As[(w * 64) * 8]);
    gload_lds16(A + (size_t)(m0 + (c1 >> 2)) * K + kofs + (c1 & 3) * 8, &As[(256 + w * 64) * 8]);
    gload_lds16(BT + (size_t)(n0 + (c0 >> 2)) * K + kofs + (c0 & 3) * 8, &Bs[(w * 64) * 8]);
    gload_lds16(BT + (size_t)(n0 + (c1 >> 2)) * K + kofs + (c1 & 3) * 8, &Bs[(256 + w * 64) * 8]);
    __syncthreads();

    short8 af[4], bfr[4];
#pragma unroll
    for (int fm = 0; fm < 4; ++fm)
      af[fm] = *(const short8*)&As[(wr * 64 + fm * 16 + lr) * 32 + lk];
#pragma unroll
    for (int fn = 0; fn < 4; ++fn)
      bfr[fn] = *(const short8*)&Bs[(wc * 64 + fn * 16 + lr) * 32 + lk];
#pragma unroll
    for (int fm = 0; fm < 4; ++fm)
#pragma unroll
      for (int fn = 0; fn < 4; ++fn)
        acc[fm][fn] = __builtin_amdgcn_mfma_f32_16x16x32_bf16(af[fm], bfr[fn], acc[fm][fn], 0, 0, 0);
  }

  // epilogue
#pragma unroll
  for (int fm = 0; fm < 4; ++fm) {
#pragma unroll
    for (int fn = 0; fn < 4; ++fn) {
#pragma unroll
      for (int r = 0; r < 4; ++r) {
        int m = m0 + wr * 64 + fm * 16 + (l >> 4) * 4 + r;
        int n = n0 + wc * 64 + fn * 16 + lr;
        float val = acc[fm][fn][r];
        if (MODE == 0) {
          if (n < 2048) {
            qkb[(size_t)m * 2048 + n] = f2b(val);
          } else {
            int hd = n - 2048;
            int head = hd >> 6, d = hd & 63;
            int b = m >> 11, t = m & 2047;
            vT[(((size_t)(b * NHEADS + head)) * 64 + d) * 2048 + t] = f2b(val);
          }
        } else {
          outf[(size_t)m * N + n] = val;
        }
      }
    }
  }
}

// ---------------- sliding-window flash attention ----------------
// qkb [8192][2048] bf16: cols 0..1023 = q (head h at h*64), 1024..2047 = k
// vT  [B*H][64][2048] bf16 (d-major)
// out: attn [8192][1024] bf16
__global__ __launch_bounds__(256) void attn_kernel(
    const u16* __restrict__ qkb, const u16* __restrict__ vT, u16* __restrict__ attn) {
  __shared__ short Qs[64 * 72];
  __shared__ short Ks[64 * 72];
  __shared__ short Vs[64 * 72];
  __shared__ short Ps[4 * 16 * 72];

  const int tid = threadIdx.x;
  const int l = tid & 63;
  const int w = tid >> 6;
  const int qt = blockIdx.x & 31;
  const int bh = blockIdx.x >> 5;   // b*16 + h
  const int b = bh >> 4, h = bh & 15;
  const int qbase = qt * 64;
  const size_t rowbase = (size_t)b * 2048;
  const int lr = l & 15, lk = (l >> 4) * 8;

  // stage Q tile [64][64] (padded rows of 72)
  for (int c = tid; c < 512; c += 256) {
    int row = c >> 3, off = (c & 7) * 8;
    *(u32x4*)&Qs[row * 72 + off] =
        *(const u32x4*)&qkb[(rowbase + qbase + row) * 2048 + h * 64 + off];
  }

  float m_run[4] = {-1e30f, -1e30f, -1e30f, -1e30f};
  float l_run[4] = {0.f, 0.f, 0.f, 0.f};
  f32x4 o[4] = {};

  int kt0 = qt - 4; if (kt0 < 0) kt0 = 0;

  for (int kt = kt0; kt <= qt; ++kt) {
    const int kbase = kt * 64;
    __syncthreads();
    for (int c = tid; c < 512; c += 256) {
      int row = c >> 3, off = (c & 7) * 8;
      *(u32x4*)&Ks[row * 72 + off] =
          *(const u32x4*)&qkb[(rowbase + kbase + row) * 2048 + 1024 + h * 64 + off];
      *(u32x4*)&Vs[row * 72 + off] =
          *(const u32x4*)&vT[((size_t)bh * 64 + row) * 2048 + kbase + off];
    }
    __syncthreads();

    // S = Q K^T  (per wave: 16 q rows x 64 keys)
    short8 aq0 = *(const short8*)&Qs[(w * 16 + lr) * 72 + lk];
    short8 aq1 = *(const short8*)&Qs[(w * 16 + lr) * 72 + 32 + lk];
    f32x4 s[4] = {};
#pragma unroll
    for (int fn = 0; fn < 4; ++fn) {
      short8 bk0 = *(const short8*)&Ks[(fn * 16 + lr) * 72 + lk];
      short8 bk1 = *(const short8*)&Ks[(fn * 16 + lr) * 72 + 32 + lk];
      s[fn] = __builtin_amdgcn_mfma_f32_16x16x32_bf16(aq0, bk0, s[fn], 0, 0, 0);
      s[fn] = __builtin_amdgcn_mfma_f32_16x16x32_bf16(aq1, bk1, s[fn], 0, 0, 0);
    }

    // mask + scale
    const int qrow0 = qbase + w * 16 + (l >> 4) * 4;
#pragma unroll
    for (int fn = 0; fn < 4; ++fn) {
      int kj = kbase + fn * 16 + lr;
#pragma unroll
      for (int r = 0; r < 4; ++r) {
        int qi = qrow0 + r;
        bool ok = (kj <= qi) && (kj >= qi - WINDOW);
        s[fn][r] = ok ? s[fn][r] * 0.125f : -1e30f;
      }
    }

    // online softmax (row reductions across 16-lane group)
    float tmax[4];
#pragma unroll
    for (int r = 0; r < 4; ++r)
      tmax[r] = fmaxf(fmaxf(s[0][r], s[1][r]), fmaxf(s[2][r], s[3][r]));
#pragma unroll
    for (int off = 1; off < 16; off <<= 1)
#pragma unroll
      for (int r = 0; r < 4; ++r)
        tmax[r] = fmaxf(tmax[r], __shfl_xor(tmax[r], off));

    float alpha[4], mnew[4], rsum[4];
#pragma unroll
    for (int r = 0; r < 4; ++r) {
      mnew[r] = fmaxf(m_run[r], tmax[r]);
      alpha[r] = __expf(m_run[r] - mnew[r]);
      m_run[r] = mnew[r];
    }
    f32x4 p[4];
#pragma unroll
    for (int fn = 0; fn < 4; ++fn)
#pragma unroll
      for (int r = 0; r < 4; ++r)
        p[fn][r] = __expf(s[fn][r] - mnew[r]);
#pragma unroll
    for (int r = 0; r < 4; ++r) rsum[r] = p[0][r] + p[1][r] + p[2][r] + p[3][r];
#pragma unroll
    for (int off = 1; off < 16; off <<= 1)
#pragma unroll
      for (int r = 0; r < 4; ++r) rsum[r] += __shfl_xor(rsum[r], off);
#pragma unroll
    for (int r = 0; r < 4; ++r) l_run[r] = l_run[r] * alpha[r] + rsum[r];
#pragma unroll
    for (int fd = 0; fd < 4; ++fd)
#pragma unroll
      for (int r = 0; r < 4; ++r) o[fd][r] *= alpha[r];

    // P -> LDS (bf16), per-wave private region
    short* Pw = &Ps[w * 16 * 72];
#pragma unroll
    for (int fn = 0; fn < 4; ++fn)
#pragma unroll
      for (int r = 0; r < 4; ++r)
        Pw[((l >> 4) * 4 + r) * 72 + fn * 16 + lr] = (short)f2b(p[fn][r]);
    asm volatile("s_waitcnt lgkmcnt(0)" ::: "memory");

    // O += P V
#pragma unroll
    for (int ks = 0; ks < 2; ++ks) {
      short8 pa = *(const short8*)&Pw[lr * 72 + ks * 32 + lk];
#pragma unroll
      for (int fd = 0; fd < 4; ++fd) {
        short8 vb = *(const short8*)&Vs[(fd * 16 + lr) * 72 + ks * 32 + lk];
        o[fd] = __builtin_amdgcn_mfma_f32_16x16x32_bf16(pa, vb, o[fd], 0, 0, 0);
      }
    }
  }

  // epilogue: O /= l, write bf16 [8192][1024]
#pragma unroll
  for (int fd = 0; fd < 4; ++fd) {
#pragma unroll
    for (int r = 0; r < 4; ++r) {
      int m = qbase + w * 16 + (l >> 4) * 4 + r;
      float val = o[fd][r] / l_run[r];
      attn[(rowbase + m) * 1024 + h * 64 + fd * 16 + lr] = f2b(val);
    }
  }
}

// ---------------- launch ----------------
extern "C" void kernel_launch(void* const* d_in, const int* in_sizes, int n_in,
                              void* d_out, int out_size, void* d_ws, size_t ws_size,
                              hipStream_t stream) {
  const float* x     = (const float*)d_in[0];
  const float* w_qkv = (const float*)d_in[1];
  const float* w_out = (const float*)d_in[2];
  float* out = (float*)d_out;
  uint8_t* ws = (uint8_t*)d_ws;

  // ws layout (bytes)
  u16* xb    = (u16*)(ws + 0);          // 8192*1024*2   = 16,777,216
  u16* wqkvT = (u16*)(ws + 16777216);   // 3072*1024*2   =  6,291,456
  u16* woutT = (u16*)(ws + 23068672);   // 1024*1024*2   =  2,097,152
  u16* qkb   = (u16*)(ws + 25165824);   // 8192*2048*2   = 33,554,432
  u16* vT    = (u16*)(ws + 58720256);   // 64*64*2048*2  = 16,777,216
  u16* attn  = (u16*)(ws + 75497472);   // 8192*1024*2   = 16,777,216  (total 92,274,688)

  cvt_cast_kernel<<<(NROWS * D_MODEL / 4 + 255) / 256, 256, 0, stream>>>(x, xb, NROWS * D_MODEL / 4);
  cvt_T_kernel<<<(3 * D_MODEL * D_MODEL + 255) / 256, 256, 0, stream>>>(w_qkv, wqkvT, D_MODEL, 3 * D_MODEL);
  cvt_T_kernel<<<(D_MODEL * D_MODEL + 255) / 256, 256, 0, stream>>>(w_out, woutT, D_MODEL, D_MODEL);

  gemm_kernel<0><<<dim3(3 * D_MODEL / 128, NROWS / 128), 256, 0, stream>>>(
      xb, wqkvT, qkb, vT, nullptr, NROWS, 3 * D_MODEL, D_MODEL);

  attn_kernel<<<BATCH * NHEADS * (SEQ / 64), 256, 0, stream>>>(qkb, vT, attn);

  gemm_kernel<1><<<dim3(D_MODEL / 128, NROWS / 128), 256, 0, stream>>>(
      attn, woutT, nullptr, nullptr, out, NROWS, D_MODEL, D_MODEL);
}

// Round 2
// 166.444 us; speedup vs baseline: 1.2097x; 1.2097x over previous
//
#include <hip/hip_runtime.h>
#include <stdint.h>

#define D_MODEL 1024
#define NHEADS  16
#define WINDOW  256
#define BATCH   4
#define SEQ     2048
#define NROWS   (BATCH*SEQ)   // 8192

using short8 = __attribute__((ext_vector_type(8))) short;
using f32x4  = __attribute__((ext_vector_type(4))) float;
using u32x4  = __attribute__((ext_vector_type(4))) uint32_t;
using u16x4  = __attribute__((ext_vector_type(4))) unsigned short;
typedef unsigned short u16;

__device__ __forceinline__ u16 f2b(float f) {
  union { float f; uint32_t u; } v; v.f = f;
  uint32_t r = v.u + 0x7fffu + ((v.u >> 16) & 1u);
  return (u16)(r >> 16);
}

__device__ __forceinline__ void gload_lds16(const void* g, void* l) {
  __builtin_amdgcn_global_load_lds(
      (const __attribute__((address_space(1))) uint32_t*)g,
      (__attribute__((address_space(3))) uint32_t*)l, 16, 0, 0);
}

// ---------------- fp32 -> bf16 straight cast ----------------
__global__ void cvt_cast_kernel(const float* __restrict__ in, u16* __restrict__ out, int n4) {
  int i = blockIdx.x * blockDim.x + threadIdx.x;
  if (i < n4) {
    f32x4 v = *(const f32x4*)(in + 4 * (size_t)i);
    u16x4 o;
    o.x = f2b(v.x); o.y = f2b(v.y); o.z = f2b(v.z); o.w = f2b(v.w);
    *(u16x4*)(out + 4 * (size_t)i) = o;
  }
}

// ---------------- tiled coalesced weight transpose: in fp32 [K][C] -> out bf16 [C][K] ----------------
__global__ __launch_bounds__(256) void cvtT_kernel(const float* __restrict__ in, u16* __restrict__ out,
                                                   int K, int C) {
  __shared__ float T[64 * 65];
  const int nbn = C >> 6;
  const int bn = blockIdx.x % nbn, bk = blockIdx.x / nbn;
  const int tid = threadIdx.x;
#pragma unroll
  for (int it = 0; it < 4; ++it) {
    int c = it * 256 + tid;
    int k = c >> 4, g = c & 15;
    f32x4 v = *(const f32x4*)&in[(size_t)(bk * 64 + k) * C + bn * 64 + g * 4];
#pragma unroll
    for (int j = 0; j < 4; ++j) T[k * 65 + g * 4 + j] = v[j];
  }
  __syncthreads();
#pragma unroll
  for (int it = 0; it < 4; ++it) {
    int c = it * 256 + tid;
    int n = c >> 4, kg = c & 15;
    u16x4 o;
#pragma unroll
    for (int j = 0; j < 4; ++j) o[j] = f2b(T[(kg * 4 + j) * 65 + n]);
    *(u16x4*)&out[(size_t)(bn * 64 + n) * K + bk * 64 + kg * 4] = o;
  }
}

// ---------------- V transpose: qkv [8192][3072] (v = cols 2048+) -> vT [bh][64 d][2048 t] ----------------
__global__ __launch_bounds__(256) void transV_kernel(const u16* __restrict__ qkv, u16* __restrict__ vT) {
  __shared__ u16 T[64 * 65];
  const int bh = blockIdx.x >> 5;   // b*16+h
  const int tt = blockIdx.x & 31;   // t-tile
  const int b = bh >> 4, h = bh & 15;
  const int tid = threadIdx.x;
#pragma unroll
  for (int it = 0; it < 2; ++it) {
    int c = it * 256 + tid;
    int t = c >> 3, g = c & 7;
    short8 v = *(const short8*)&qkv[(size_t)(b * 2048 + tt * 64 + t) * 3072 + 2048 + h * 64 + g * 8];
#pragma unroll
    for (int j = 0; j < 8; ++j) T[t * 65 + g * 8 + j] = (u16)v[j];
  }
  __syncthreads();
#pragma unroll
  for (int it = 0; it < 2; ++it) {
    int c = it * 256 + tid;
    int d = c >> 3, tg = c & 7;
    short8 o;
#pragma unroll
    for (int j = 0; j < 8; ++j) o[j] = (short)T[(tg * 8 + j) * 65 + d];
    *(short8*)&vT[((size_t)bh * 64 + d) * 2048 + tt * 64 + tg * 8] = o;
  }
}

// ---------------- GEMM: 2-phase double-buffered, BM=128 BN=256 BK=64, 8 waves ----------------
// A [M][K] bf16, BT [N][K] bf16 (pre-transposed). MODE 0: bf16 out [M][N]; MODE 1: fp32 out [M][N].
template <int MODE>
__global__ __launch_bounds__(512, 2) void gemm_kernel(
    const u16* __restrict__ A, const u16* __restrict__ BT,
    u16* __restrict__ outb, float* __restrict__ outf,
    int M, int N, int K, int nbx) {
  __shared__ short As[2][128 * 64];
  __shared__ short Bs[2][256 * 64];
  const int tid = threadIdx.x;
  const int l = tid & 63;
  const int w = tid >> 6;
  const int lr = l & 15, lk = (l >> 4) * 8;
  const int wr = w >> 2, wc = w & 3;

  // T1: bijective XCD swizzle (grids are multiples of 8)
  const int nwg = gridDim.x;
  const int lid = blockIdx.x;
  const int wg = (lid & 7) * (nwg >> 3) + (lid >> 3);
  const int bx = wg % nbx, by = wg / nbx;
  const int m0 = by * 128, n0 = bx * 256;

  const int sw = (lr & 7) << 3;   // T2 read-side XOR (shorts)
  const int NKT = K >> 6;
  f32x4 acc[4][4] = {};

  auto stage = [&](int buf, int kt) {
    const int kk = kt << 6;
#pragma unroll
    for (int ln = 0; ln < 2; ++ln) {
      int c = ln * 512 + tid;
      int row = c >> 3;
      int gs = (c & 7) ^ (row & 7);   // T2: pre-swizzled global source granule
      gload_lds16(A + (size_t)(m0 + row) * K + kk + gs * 8,
                  &As[buf][(ln * 512 + w * 64) * 8]);
    }
#pragma unroll
    for (int ln = 0; ln < 4; ++ln) {
      int c = ln * 512 + tid;
      int row = c >> 3;
      int gs = (c & 7) ^ (row & 7);
      gload_lds16(BT + (size_t)(n0 + row) * K + kk + gs * 8,
                  &Bs[buf][(ln * 512 + w * 64) * 8]);
    }
  };

  stage(0, 0);
  __syncthreads();
  int cur = 0;
  for (int kt = 0; kt < NKT; ++kt) {
    if (kt + 1 < NKT) stage(cur ^ 1, kt + 1);   // issue next-tile loads BEFORE compute
    short8 af[2][4], bfr[2][4];
#pragma unroll
    for (int kh = 0; kh < 2; ++kh) {
      const int ko = (kh * 32 + lk) ^ sw;
#pragma unroll
      for (int fm = 0; fm < 4; ++fm)
        af[kh][fm] = *(const short8*)&As[cur][(wr * 64 + fm * 16 + lr) * 64 + ko];
#pragma unroll
      for (int fn = 0; fn < 4; ++fn)
        bfr[kh][fn] = *(const short8*)&Bs[cur][(wc * 64 + fn * 16 + lr) * 64 + ko];
    }
#pragma unroll
    for (int kh = 0; kh < 2; ++kh)
#pragma unroll
      for (int fm = 0; fm < 4; ++fm)
#pragma unroll
        for (int fn = 0; fn < 4; ++fn)
          acc[fm][fn] = __builtin_amdgcn_mfma_f32_16x16x32_bf16(af[kh][fm], bfr[kh][fn], acc[fm][fn], 0, 0, 0);
    __syncthreads();   // vmcnt(0)+lgkmcnt(0)+barrier: next buffer ready, cur free to overwrite
    cur ^= 1;
  }

  // epilogue
#pragma unroll
  for (int fm = 0; fm < 4; ++fm) {
    const int m = m0 + wr * 64 + fm * 16 + (l >> 4) * 4;
#pragma unroll
    for (int fn = 0; fn < 4; ++fn) {
      const int n = n0 + wc * 64 + fn * 16 + lr;
#pragma unroll
      for (int r = 0; r < 4; ++r) {
        if (MODE == 0) outb[(size_t)(m + r) * N + n] = f2b(acc[fm][fn][r]);
        else           outf[(size_t)(m + r) * N + n] = acc[fm][fn][r];
      }
    }
  }
}

// ---------------- sliding-window flash attention ----------------
// qkv [8192][3072] bf16: q at h*64, k at 1024+h*64.  vT [bh][64][2048] bf16.
// out: attn [8192][1024] bf16
__global__ __launch_bounds__(256) void attn_kernel(
    const u16* __restrict__ qkv, const u16* __restrict__ vT, u16* __restrict__ attn) {
  __shared__ short Qs[64 * 72];
  __shared__ short Ks[64 * 72];
  __shared__ short Vs[64 * 72];
  __shared__ short Ps[4 * 16 * 72];

  const int tid = threadIdx.x;
  const int l = tid & 63;
  const int w = tid >> 6;
  const int qt = blockIdx.x & 31;
  const int bh = blockIdx.x >> 5;   // b*16 + h
  const int b = bh >> 4, h = bh & 15;
  const int qbase = qt * 64;
  const size_t rowbase = (size_t)b * 2048;
  const int lr = l & 15, lk = (l >> 4) * 8;

  for (int c = tid; c < 512; c += 256) {
    int row = c >> 3, off = (c & 7) * 8;
    *(u32x4*)&Qs[row * 72 + off] =
        *(const u32x4*)&qkv[(rowbase + qbase + row) * 3072 + h * 64 + off];
  }

  float m_run[4] = {-1e30f, -1e30f, -1e30f, -1e30f};
  float l_run[4] = {0.f, 0.f, 0.f, 0.f};
  f32x4 o[4] = {};

  int kt0 = qt - 4; if (kt0 < 0) kt0 = 0;

  for (int kt = kt0; kt <= qt; ++kt) {
    const int kbase = kt * 64;
    __syncthreads();
    for (int c = tid; c < 512; c += 256) {
      int row = c >> 3, off = (c & 7) * 8;
      *(u32x4*)&Ks[row * 72 + off] =
          *(const u32x4*)&qkv[(rowbase + kbase + row) * 3072 + 1024 + h * 64 + off];
      *(u32x4*)&Vs[row * 72 + off] =
          *(const u32x4*)&vT[((size_t)bh * 64 + row) * 2048 + kbase + off];
    }
    __syncthreads();

    short8 aq0 = *(const short8*)&Qs[(w * 16 + lr) * 72 + lk];
    short8 aq1 = *(const short8*)&Qs[(w * 16 + lr) * 72 + 32 + lk];
    f32x4 s[4] = {};
#pragma unroll
    for (int fn = 0; fn < 4; ++fn) {
      short8 bk0 = *(const short8*)&Ks[(fn * 16 + lr) * 72 + lk];
      short8 bk1 = *(const short8*)&Ks[(fn * 16 + lr) * 72 + 32 + lk];
      s[fn] = __builtin_amdgcn_mfma_f32_16x16x32_bf16(aq0, bk0, s[fn], 0, 0, 0);
      s[fn] = __builtin_amdgcn_mfma_f32_16x16x32_bf16(aq1, bk1, s[fn], 0, 0, 0);
    }

    const int qrow0 = qbase + w * 16 + (l >> 4) * 4;
#pragma unroll
    for (int fn = 0; fn < 4; ++fn) {
      int kj = kbase + fn * 16 + lr;
#pragma unroll
      for (int r = 0; r < 4; ++r) {
        int qi = qrow0 + r;
        bool ok = (kj <= qi) && (kj >= qi - WINDOW);
        s[fn][r] = ok ? s[fn][r] * 0.125f : -1e30f;
      }
    }

    float tmax[4];
#pragma unroll
    for (int r = 0; r < 4; ++r)
      tmax[r] = fmaxf(fmaxf(s[0][r], s[1][r]), fmaxf(s[2][r], s[3][r]));
#pragma unroll
    for (int off = 1; off < 16; off <<= 1)
#pragma unroll
      for (int r = 0; r < 4; ++r)
        tmax[r] = fmaxf(tmax[r], __shfl_xor(tmax[r], off));

    float alpha[4], mnew[4], rsum[4];
#pragma unroll
    for (int r = 0; r < 4; ++r) {
      mnew[r] = fmaxf(m_run[r], tmax[r]);
      alpha[r] = __expf(m_run[r] - mnew[r]);
      m_run[r] = mnew[r];
    }
    f32x4 p[4];
#pragma unroll
    for (int fn = 0; fn < 4; ++fn)
#pragma unroll
      for (int r = 0; r < 4; ++r)
        p[fn][r] = __expf(s[fn][r] - mnew[r]);
#pragma unroll
    for (int r = 0; r < 4; ++r) rsum[r] = p[0][r] + p[1][r] + p[2][r] + p[3][r];
#pragma unroll
    for (int off = 1; off < 16; off <<= 1)
#pragma unroll
      for (int r = 0; r < 4; ++r) rsum[r] += __shfl_xor(rsum[r], off);
#pragma unroll
    for (int r = 0; r < 4; ++r) l_run[r] = l_run[r] * alpha[r] + rsum[r];
#pragma unroll
    for (int fd = 0; fd < 4; ++fd)
#pragma unroll
      for (int r = 0; r < 4; ++r) o[fd][r] *= alpha[r];

    short* Pw = &Ps[w * 16 * 72];
#pragma unroll
    for (int fn = 0; fn < 4; ++fn)
#pragma unroll
      for (int r = 0; r < 4; ++r)
        Pw[((l >> 4) * 4 + r) * 72 + fn * 16 + lr] = (short)f2b(p[fn][r]);
    asm volatile("s_waitcnt lgkmcnt(0)" ::: "memory");

#pragma unroll
    for (int ks = 0; ks < 2; ++ks) {
      short8 pa = *(const short8*)&Pw[lr * 72 + ks * 32 + lk];
#pragma unroll
      for (int fd = 0; fd < 4; ++fd) {
        short8 vb = *(const short8*)&Vs[(fd * 16 + lr) * 72 + ks * 32 + lk];
        o[fd] = __builtin_amdgcn_mfma_f32_16x16x32_bf16(pa, vb, o[fd], 0, 0, 0);
      }
    }
  }

#pragma unroll
  for (int fd = 0; fd < 4; ++fd) {
#pragma unroll
    for (int r = 0; r < 4; ++r) {
      int m = qbase + w * 16 + (l >> 4) * 4 + r;
      float val = o[fd][r] / l_run[r];
      attn[(rowbase + m) * 1024 + h * 64 + fd * 16 + lr] = f2b(val);
    }
  }
}

// ---------------- launch ----------------
extern "C" void kernel_launch(void* const* d_in, const int* in_sizes, int n_in,
                              void* d_out, int out_size, void* d_ws, size_t ws_size,
                              hipStream_t stream) {
  const float* x     = (const float*)d_in[0];
  const float* w_qkv = (const float*)d_in[1];
  const float* w_out = (const float*)d_in[2];
  float* out = (float*)d_out;
  uint8_t* ws = (uint8_t*)d_ws;

  // ws layout (bytes) — total 92,274,688
  u16* xb    = (u16*)(ws + 0);          // 8192*1024*2 = 16,777,216 ; reused as attn output
  u16* wqkvT = (u16*)(ws + 16777216);   // 3072*1024*2 =  6,291,456
  u16* woutT = (u16*)(ws + 23068672);   // 1024*1024*2 =  2,097,152
  u16* qkv   = (u16*)(ws + 25165824);   // 8192*3072*2 = 50,331,648
  u16* vT    = (u16*)(ws + 75497472);   // 64*64*2048*2= 16,777,216

  cvt_cast_kernel<<<(NROWS * D_MODEL / 4 + 255) / 256, 256, 0, stream>>>(x, xb, NROWS * D_MODEL / 4);
  cvtT_kernel<<<(3 * D_MODEL / 64) * (D_MODEL / 64), 256, 0, stream>>>(w_qkv, wqkvT, D_MODEL, 3 * D_MODEL);
  cvtT_kernel<<<(D_MODEL / 64) * (D_MODEL / 64), 256, 0, stream>>>(w_out, woutT, D_MODEL, D_MODEL);

  gemm_kernel<0><<<(3 * D_MODEL / 256) * (NROWS / 128), 512, 0, stream>>>(
      xb, wqkvT, qkv, nullptr, NROWS, 3 * D_MODEL, D_MODEL, 3 * D_MODEL / 256);

  transV_kernel<<<BATCH * NHEADS * (SEQ / 64), 256, 0, stream>>>(qkv, vT);

  attn_kernel<<<BATCH * NHEADS * (SEQ / 64), 256, 0, stream>>>(qkv, vT, xb);

  gemm_kernel<1><<<(D_MODEL / 256) * (NROWS / 128), 512, 0, stream>>>(
      xb, woutT, nullptr, out, NROWS, D_MODEL, D_MODEL, D_MODEL / 256);
}